// Round 1
// baseline (2750.920 us; speedup 1.0000x reference)
//
#include <hip/hip_runtime.h>
#include <math.h>

#define BB 16
#define CC 512
#define LL 1024
#define NHEAD 8
#define DH 64
#define KW 7

// ---------------- timing signal add: out[b,c,l] = x + sig(l,c) ----------------
__global__ void k_addts(const float* __restrict__ x, float* __restrict__ out) {
  int idx = blockIdx.x * 256 + threadIdx.x;
  int l = idx & (LL - 1);
  int c = (idx >> 10) & (CC - 1);
  const float log_inc = 9.210340371976184f / 255.0f;  // log(10000)/(nt-1), nt=256
  int j = c & 255;
  float inv = expf(-(float)j * log_inc);
  float st = (float)l * inv;
  float sig = (c < 256) ? sinf(st) : cosf(st);
  out[idx] = x[idx] + sig;
}

// ---------------- layernorm over channel dim, (B,C,L) layout ----------------
// block 512 = 64 l-positions x 8 channel-groups of 64 channels
__global__ __launch_bounds__(512) void k_ln(const float* __restrict__ in,
                                            const float* __restrict__ g,
                                            const float* __restrict__ bb,
                                            float* __restrict__ out) {
  int lq = threadIdx.x & 63;
  int cg = threadIdx.x >> 6;  // 0..7
  int l = blockIdx.x * 64 + lq;
  int b = blockIdx.y;
  const float* p = in + (size_t)b * CC * LL + l;
  float s = 0.f, ss = 0.f;
  for (int c = cg * 64; c < cg * 64 + 64; ++c) {
    float v = p[(size_t)c * LL];
    s += v; ss += v * v;
  }
  __shared__ float red[2][8][64];
  __shared__ float mv[2][64];
  red[0][cg][lq] = s; red[1][cg][lq] = ss;
  __syncthreads();
  if (cg == 0) {
    float ts = 0.f, tss = 0.f;
    for (int u = 0; u < 8; ++u) { ts += red[0][u][lq]; tss += red[1][u][lq]; }
    float mean = ts * (1.0f / CC);
    float var = tss * (1.0f / CC) - mean * mean;
    mv[0][lq] = mean;
    mv[1][lq] = rsqrtf(var + 1e-5f);
  }
  __syncthreads();
  float mean = mv[0][lq], rstd = mv[1][lq];
  float* q = out + (size_t)b * CC * LL + l;
  for (int c = cg * 64; c < cg * 64 + 64; ++c) {
    float v = p[(size_t)c * LL];
    q[(size_t)c * LL] = (v - mean) * rstd * g[c] + bb[c];
  }
}

// ---------------- depthwise conv K=7, pad 3, along L ----------------
__global__ void k_dwconv(const float* __restrict__ in, const float* __restrict__ w,
                         float* __restrict__ out) {
  int idx = blockIdx.x * 256 + threadIdx.x;
  int l = idx & (LL - 1);
  int bc = idx >> 10;       // b*CC + c
  int c = bc & (CC - 1);
  const float* p = in + (size_t)bc * LL;
  float s = 0.f;
#pragma unroll
  for (int k = 0; k < KW; ++k) {
    int li = l + k - 3;
    float v = (li >= 0 && li < LL) ? p[li] : 0.f;
    s += w[c * KW + k] * v;
  }
  out[idx] = s;
}

// ---------------- fp32 GEMM: Y[b,m,l] = act(sum_k W[m,k] X[b,k,l] + bias[m]) ----
// M = 512 always (output stride). Tiles 128x128, BK=16, 256 thr, 8x8 microtile.
template <int RELU>
__global__ __launch_bounds__(256) void k_gemm(const float* __restrict__ W,
                                              const float* __restrict__ X,
                                              const float* __restrict__ bias,
                                              float* __restrict__ Y, int K) {
  __shared__ float As[16][128];  // As[k][m]
  __shared__ float Bs[16][128];  // Bs[k][n]
  int t = threadIdx.x;
  int tx = t & 15, ty = t >> 4;
  int n0 = blockIdx.x * 128;
  int m0 = blockIdx.y * 128;
  int b = blockIdx.z;
  const float* Xb = X + (size_t)b * K * LL;
  float acc[8][8] = {};
  for (int k0 = 0; k0 < K; k0 += 16) {
    {
      int idx = t;
#pragma unroll
      for (int r = 0; r < 2; ++r) {
        int m = idx >> 2, kq = idx & 3;
        float4 w4 = *(const float4*)&W[(size_t)(m0 + m) * K + k0 + kq * 4];
        As[kq * 4 + 0][m] = w4.x; As[kq * 4 + 1][m] = w4.y;
        As[kq * 4 + 2][m] = w4.z; As[kq * 4 + 3][m] = w4.w;
        idx += 256;
      }
      idx = t;
#pragma unroll
      for (int r = 0; r < 2; ++r) {
        int k = idx >> 5, nq = idx & 31;
        *(float4*)&Bs[k][nq * 4] =
            *(const float4*)&Xb[(size_t)(k0 + k) * LL + n0 + nq * 4];
        idx += 256;
      }
    }
    __syncthreads();
#pragma unroll
    for (int k = 0; k < 16; ++k) {
      float4 a0 = *(const float4*)&As[k][ty * 8];
      float4 a1 = *(const float4*)&As[k][ty * 8 + 4];
      float4 b0 = *(const float4*)&Bs[k][tx * 8];
      float4 b1 = *(const float4*)&Bs[k][tx * 8 + 4];
      float av[8] = {a0.x, a0.y, a0.z, a0.w, a1.x, a1.y, a1.z, a1.w};
      float bv[8] = {b0.x, b0.y, b0.z, b0.w, b1.x, b1.y, b1.z, b1.w};
#pragma unroll
      for (int i = 0; i < 8; ++i)
#pragma unroll
        for (int j = 0; j < 8; ++j) acc[i][j] += av[i] * bv[j];
    }
    __syncthreads();
  }
  float* Yb = Y + (size_t)b * 512 * LL;
#pragma unroll
  for (int i = 0; i < 8; ++i) {
    int m = m0 + ty * 8 + i;
    float bi = bias[m];
    float v[8];
#pragma unroll
    for (int j = 0; j < 8; ++j) {
      float o = acc[i][j] + bi;
      if (RELU) o = fmaxf(o, 0.f);
      v[j] = o;
    }
    float4 o0 = {v[0], v[1], v[2], v[3]};
    float4 o1 = {v[4], v[5], v[6], v[7]};
    *(float4*)&Yb[(size_t)m * LL + n0 + tx * 8] = o0;
    *(float4*)&Yb[(size_t)m * LL + n0 + tx * 8 + 4] = o1;
  }
}

// ---------------- attention: Q,K,V in (B,C,L) d-major layout ----------------
// grid (L/64, NHEAD, B), block 256. Flash-style, no-max softmax (logits ~ +-2).
__global__ __launch_bounds__(256) void k_attn(const float* __restrict__ Q,
                                              const float* __restrict__ Kp,
                                              const float* __restrict__ Vp,
                                              const int* __restrict__ mask,
                                              float* __restrict__ out) {
  __shared__ float Qs[64][68];  // Qs[d][q]
  __shared__ float Ks[64][68];  // Ks[d][k]
  __shared__ float Vs[64][68];  // Vs[k][d]
  __shared__ float Ps[64][68];  // Ps[q][k]
  __shared__ float ms[64];
  int t = threadIdx.x;
  int tx = t & 15, ty = t >> 4;
  int q0 = blockIdx.x * 64;
  int h = blockIdx.y, b = blockIdx.z;
  size_t base = ((size_t)b * CC + h * DH) * LL;

  for (int idx = t; idx < 64 * 16; idx += 256) {
    int d = idx >> 4, qq = (idx & 15) * 4;
    float4 v = *(const float4*)&Q[base + (size_t)d * LL + q0 + qq];
    Qs[d][qq + 0] = v.x * 0.125f; Qs[d][qq + 1] = v.y * 0.125f;
    Qs[d][qq + 2] = v.z * 0.125f; Qs[d][qq + 3] = v.w * 0.125f;
  }

  float acc[4][4] = {};
  float rowsum[4] = {};
  for (int kt = 0; kt < LL / 64; ++kt) {
    int k0 = kt * 64;
    __syncthreads();  // protect Ks/Vs/Ps from previous iteration readers
    for (int idx = t; idx < 64 * 16; idx += 256) {
      int d = idx >> 4, kq = (idx & 15) * 4;
      float4 v = *(const float4*)&Kp[base + (size_t)d * LL + k0 + kq];
      Ks[d][kq + 0] = v.x; Ks[d][kq + 1] = v.y;
      Ks[d][kq + 2] = v.z; Ks[d][kq + 3] = v.w;
      float4 w = *(const float4*)&Vp[base + (size_t)d * LL + k0 + kq];
      Vs[kq + 0][d] = w.x; Vs[kq + 1][d] = w.y;
      Vs[kq + 2][d] = w.z; Vs[kq + 3][d] = w.w;
    }
    if (t < 64) ms[t] = (mask[(size_t)b * LL + k0 + t] != 0) ? 1.f : 0.f;
    __syncthreads();

    float s[4][4] = {};
#pragma unroll
    for (int d = 0; d < 64; ++d) {
      float4 aq = *(const float4*)&Qs[d][ty * 4];
      float4 bk = *(const float4*)&Ks[d][tx * 4];
      float aqv[4] = {aq.x, aq.y, aq.z, aq.w};
      float bkv[4] = {bk.x, bk.y, bk.z, bk.w};
#pragma unroll
      for (int i = 0; i < 4; ++i)
#pragma unroll
        for (int j = 0; j < 4; ++j) s[i][j] += aqv[i] * bkv[j];
    }
    float4 mk = *(const float4*)&ms[tx * 4];
    float mkv[4] = {mk.x, mk.y, mk.z, mk.w};
#pragma unroll
    for (int i = 0; i < 4; ++i) {
      float pv[4];
#pragma unroll
      for (int j = 0; j < 4; ++j) {
        float p = (mkv[j] != 0.f) ? __expf(s[i][j]) : 0.f;
        pv[j] = p;
        rowsum[i] += p;
      }
      float4 pr = {pv[0], pv[1], pv[2], pv[3]};
      *(float4*)&Ps[ty * 4 + i][tx * 4] = pr;
    }
    __syncthreads();

#pragma unroll
    for (int kk = 0; kk < 64; kk += 4) {
      float4 p0 = *(const float4*)&Ps[ty * 4 + 0][kk];
      float4 p1 = *(const float4*)&Ps[ty * 4 + 1][kk];
      float4 p2 = *(const float4*)&Ps[ty * 4 + 2][kk];
      float4 p3 = *(const float4*)&Ps[ty * 4 + 3][kk];
      float4 v0 = *(const float4*)&Vs[kk + 0][tx * 4];
      float4 v1 = *(const float4*)&Vs[kk + 1][tx * 4];
      float4 v2 = *(const float4*)&Vs[kk + 2][tx * 4];
      float4 v3 = *(const float4*)&Vs[kk + 3][tx * 4];
      float pA[4][4] = {{p0.x, p0.y, p0.z, p0.w},
                        {p1.x, p1.y, p1.z, p1.w},
                        {p2.x, p2.y, p2.z, p2.w},
                        {p3.x, p3.y, p3.z, p3.w}};
      float vA[4][4] = {{v0.x, v0.y, v0.z, v0.w},
                        {v1.x, v1.y, v1.z, v1.w},
                        {v2.x, v2.y, v2.z, v2.w},
                        {v3.x, v3.y, v3.z, v3.w}};
#pragma unroll
      for (int i = 0; i < 4; ++i)
#pragma unroll
        for (int j = 0; j < 4; ++j)
#pragma unroll
          for (int u = 0; u < 4; ++u) acc[i][j] += pA[i][u] * vA[u][j];
    }
  }

  __syncthreads();
#pragma unroll
  for (int i = 0; i < 4; ++i) Ps[ty * 4 + i][tx] = rowsum[i];
  __syncthreads();
  float inv[4];
#pragma unroll
  for (int i = 0; i < 4; ++i) {
    float den = 0.f;
#pragma unroll
    for (int u = 0; u < 16; ++u) den += Ps[ty * 4 + i][u];
    inv[i] = 1.f / den;
  }
#pragma unroll
  for (int i = 0; i < 4; ++i)
#pragma unroll
    for (int j = 0; j < 4; ++j)
      out[base + (size_t)(tx * 4 + j) * LL + q0 + ty * 4 + i] = acc[i][j] * inv[i];
}

extern "C" void kernel_launch(void* const* d_in, const int* in_sizes, int n_in,
                              void* d_out, int out_size, void* d_ws, size_t ws_size,
                              hipStream_t stream) {
  const float* x        = (const float*)d_in[0];
  const int*   mask     = (const int*)d_in[1];
  // d_in[2]=layer, d_in[3]=num_blks (unused)
  const float* dw_w     = (const float*)d_in[4];
  const float* pw_w     = (const float*)d_in[5];
  const float* pw_b     = (const float*)d_in[6];
  const float* cln_g    = (const float*)d_in[7];
  const float* cln_b    = (const float*)d_in[8];
  const float* w_kv     = (const float*)d_in[9];
  const float* b_kv     = (const float*)d_in[10];
  const float* w_q      = (const float*)d_in[11];
  const float* b_q      = (const float*)d_in[12];
  const float* ln_att_g = (const float*)d_in[13];
  const float* ln_att_b = (const float*)d_in[14];
  const float* w_ffd1   = (const float*)d_in[15];
  const float* b_ffd1   = (const float*)d_in[16];
  const float* w_ffd2   = (const float*)d_in[17];
  const float* b_ffd2   = (const float*)d_in[18];
  const float* ln_ffd_g = (const float*)d_in[19];
  const float* ln_ffd_b = (const float*)d_in[20];
  float* out = (float*)d_out;

  size_t tsz = (size_t)BB * CC * LL;
  float* P0 = (float*)d_ws;
  float* P1 = P0 + tsz;
  float* P2 = P1 + tsz;

  int total = BB * CC * LL;
  dim3 b256(256);
  dim3 lngrid(LL / 64, BB);
  dim3 ggrid(LL / 128, 4, BB);

  k_addts<<<total / 256, b256, 0, stream>>>(x, P0);

  for (int i = 0; i < 4; ++i) {
    k_ln<<<lngrid, 512, 0, stream>>>(P0, cln_g + i * CC, cln_b + i * CC, P1);
    k_dwconv<<<total / 256, b256, 0, stream>>>(P1, dw_w + i * CC * KW, P2);
    k_gemm<1><<<ggrid, b256, 0, stream>>>(pw_w + (size_t)i * CC * CC, P2,
                                          pw_b + i * CC, P0, CC);
  }

  k_ln<<<lngrid, 512, 0, stream>>>(P0, ln_att_g, ln_att_b, P1);
  k_gemm<0><<<ggrid, b256, 0, stream>>>(w_kv, P1, b_kv, P0, CC);              // K
  k_gemm<0><<<ggrid, b256, 0, stream>>>(w_kv + CC * CC, P1, b_kv + CC, P2, CC); // V
  k_gemm<0><<<ggrid, b256, 0, stream>>>(w_q, P1, b_q, out, CC);               // Q (d_out scratch)
  k_attn<<<dim3(LL / 64, NHEAD, BB), b256, 0, stream>>>(out, P0, P2, mask, P1);

  k_ln<<<lngrid, 512, 0, stream>>>(P1, ln_ffd_g, ln_ffd_b, P0);
  k_gemm<1><<<ggrid, b256, 0, stream>>>(w_ffd1, P0, b_ffd1, P2, CC);
  k_gemm<0><<<ggrid, b256, 0, stream>>>(w_ffd2, P2, b_ffd2, out, CC);
}

// Round 2
// 523.783 us; speedup vs baseline: 5.2520x; 5.2520x over previous
//
#include <hip/hip_runtime.h>
#include <math.h>

#define BB 16
#define CC 512
#define LL 1024
#define NHEAD 8
#define DH 64
#define KW 7

typedef unsigned short us8 __attribute__((ext_vector_type(8)));
typedef unsigned short us4 __attribute__((ext_vector_type(4)));
typedef short mbf8 __attribute__((ext_vector_type(8)));
typedef float f32x4 __attribute__((ext_vector_type(4)));

__device__ inline unsigned short f2bf(float f) {
  union { float f; unsigned int u; } v; v.f = f;
  unsigned int u = v.u;
  u += 0x7fffu + ((u >> 16) & 1u);
  return (unsigned short)(u >> 16);
}
__device__ inline float bf2f(unsigned short s) {
  union { unsigned int u; float f; } v; v.u = ((unsigned int)s) << 16;
  return v.f;
}

// ---- weight fp32 -> bf16 pre-convert (pw_w, w_kv, w_q, w_ffd1, w_ffd2) ----
__global__ __launch_bounds__(256) void k_cvtW(const float* __restrict__ p0,
                                              const float* __restrict__ p1,
                                              const float* __restrict__ p2,
                                              const float* __restrict__ p3,
                                              const float* __restrict__ p4,
                                              unsigned short* __restrict__ dst) {
  int idx = blockIdx.x * 256 + threadIdx.x;
  int e = idx * 4;
  const int n0 = 4 * CC * CC, n1 = 2 * CC * CC, n2 = CC * CC;
  const float* src; int off;
  if (e < n0)                { src = p0; off = e; }
  else if (e < n0 + n1)      { src = p1; off = e - n0; }
  else if (e < n0 + n1 + n2) { src = p2; off = e - n0 - n1; }
  else if (e < n0 + n1 + 2 * n2) { src = p3; off = e - n0 - n1 - n2; }
  else                       { src = p4; off = e - n0 - n1 - 2 * n2; }
  float4 v = *(const float4*)(src + off);
  us4 o; o[0] = f2bf(v.x); o[1] = f2bf(v.y); o[2] = f2bf(v.z); o[3] = f2bf(v.w);
  *(us4*)(dst + e) = o;
}

// ---- x (B,C,L) f32 -> Act (B,L,C) bf16 with timing signal added ----
__global__ __launch_bounds__(256) void k_in_tr(const float* __restrict__ x,
                                               unsigned short* __restrict__ act) {
  __shared__ float xt[64][69];
  int t = threadIdx.x;
  int c0 = blockIdx.x * 64;
  int l0 = blockIdx.y * 64;
  int b  = blockIdx.z;
  {
    int r = t >> 2, lo = (t & 3) * 16;
    const float* src = x + ((size_t)b * CC + c0 + r) * LL + l0 + lo;
#pragma unroll
    for (int q = 0; q < 4; ++q) {
      float4 v = *(const float4*)(src + q * 4);
      xt[r][lo + q * 4 + 0] = v.x; xt[r][lo + q * 4 + 1] = v.y;
      xt[r][lo + q * 4 + 2] = v.z; xt[r][lo + q * 4 + 3] = v.w;
    }
  }
  __syncthreads();
  const float log_inc = 9.210340371976184f / 255.0f;
  int lr = t >> 2, co = (t & 3) * 16;
  int l = l0 + lr;
  unsigned short obuf[16];
#pragma unroll
  for (int u = 0; u < 16; ++u) {
    int c = c0 + co + u;
    float inv = __expf(-(float)(c & 255) * log_inc);
    float st = (float)l * inv;
    float sg = (c < 256) ? sinf(st) : cosf(st);
    obuf[u] = f2bf(xt[co + u][lr] + sg);
  }
  unsigned short* dst = act + ((size_t)b * LL + l) * CC + c0 + co;
  *(us8*)dst = *(us8*)&obuf[0];
  *(us8*)(dst + 8) = *(us8*)&obuf[8];
}

// ---- row LayerNorm over C, (B,L,C) bf16 ----
__global__ __launch_bounds__(256) void k_ln(const unsigned short* __restrict__ in,
                                            const float* __restrict__ g,
                                            const float* __restrict__ bta,
                                            unsigned short* __restrict__ out) {
  int t = threadIdx.x;
  int lane = t & 63, w = t >> 6;
  size_t row = (size_t)blockIdx.x * 4 + w;
  const unsigned short* p = in + row * CC + lane * 8;
  us8 v = *(const us8*)p;
  float f[8]; float s = 0.f, ss = 0.f;
#pragma unroll
  for (int i = 0; i < 8; ++i) { f[i] = bf2f(v[i]); s += f[i]; ss += f[i] * f[i]; }
#pragma unroll
  for (int m = 1; m < 64; m <<= 1) { s += __shfl_xor(s, m); ss += __shfl_xor(ss, m); }
  float mean = s * (1.f / CC);
  float rstd = rsqrtf(ss * (1.f / CC) - mean * mean + 1e-5f);
  float4 g0 = *(const float4*)(g + lane * 8), g1 = *(const float4*)(g + lane * 8 + 4);
  float4 b0 = *(const float4*)(bta + lane * 8), b1 = *(const float4*)(bta + lane * 8 + 4);
  float gg[8] = {g0.x, g0.y, g0.z, g0.w, g1.x, g1.y, g1.z, g1.w};
  float bb2[8] = {b0.x, b0.y, b0.z, b0.w, b1.x, b1.y, b1.z, b1.w};
  unsigned short o[8];
#pragma unroll
  for (int i = 0; i < 8; ++i) o[i] = f2bf((f[i] - mean) * rstd * gg[i] + bb2[i]);
  *(us8*)(out + row * CC + lane * 8) = *(us8*)&o[0];
}

// ---- depthwise conv K=7 along L, (B,L,C) bf16, fp32 weights ----
__global__ __launch_bounds__(256) void k_dwconv(const unsigned short* __restrict__ in,
                                                const float* __restrict__ w,
                                                unsigned short* __restrict__ out) {
  __shared__ float wld[CC * KW];
  int t = threadIdx.x;
  for (int i = t; i < CC * KW; i += 256) wld[i] = w[i];
  __syncthreads();
  int c = (t & 63) * 8;
  int rowid = blockIdx.x * 4 + (t >> 6);
  int l = rowid & (LL - 1);
  int b = rowid >> 10;
  float acc[8] = {};
#pragma unroll
  for (int j = 0; j < KW; ++j) {
    int lj = l + j - 3;
    if (lj < 0 || lj >= LL) continue;
    us8 v = *(const us8*)(in + ((size_t)b * LL + lj) * CC + c);
#pragma unroll
    for (int u = 0; u < 8; ++u) acc[u] += bf2f(v[u]) * wld[(c + u) * KW + j];
  }
  unsigned short o[8];
#pragma unroll
  for (int u = 0; u < 8; ++u) o[u] = f2bf(acc[u]);
  *(us8*)(out + ((size_t)b * LL + l) * CC + c) = *(us8*)&o[0];
}

// ---- MFMA GEMM: D[i][j] = sum_k A[i][k]*B[j][k] (+bias, relu) ----
// A,B row-major bf16 with row stride 512 (k contiguous). 128x128 tile, BK=64.
template <int RELU, int F32OUT, int BIASI>
__global__ __launch_bounds__(256) void k_gemm(const unsigned short* __restrict__ A,
                                              long Ab,
                                              const unsigned short* __restrict__ Bm,
                                              long Bb,
                                              const float* __restrict__ bias,
                                              void* __restrict__ outp,
                                              long orow, long obatch) {
  __shared__ __align__(16) unsigned short Ald[128][72];
  __shared__ __align__(16) unsigned short Bld[128][72];
  int t = threadIdx.x;
  int lane = t & 63, w = t >> 6;
  int wi = w >> 1, wj = w & 1;
  int i0 = blockIdx.y * 128, j0 = blockIdx.x * 128;
  const unsigned short* Ag = A + (size_t)blockIdx.z * Ab + (size_t)i0 * 512;
  const unsigned short* Bg = Bm + (size_t)blockIdx.z * Bb + (size_t)j0 * 512;
  f32x4 acc[4][4];
  const f32x4 fz = {0.f, 0.f, 0.f, 0.f};
#pragma unroll
  for (int a = 0; a < 4; ++a)
#pragma unroll
    for (int c = 0; c < 4; ++c) acc[a][c] = fz;
  int srow = t >> 2, sko = (t & 3) * 16;
  for (int k0 = 0; k0 < 512; k0 += 64) {
    __syncthreads();
#pragma unroll
    for (int it = 0; it < 2; ++it) {
      int r = srow + it * 64;
      const unsigned short* pa = Ag + (size_t)r * 512 + k0 + sko;
      *(us8*)&Ald[r][sko]     = *(const us8*)pa;
      *(us8*)&Ald[r][sko + 8] = *(const us8*)(pa + 8);
      const unsigned short* pb = Bg + (size_t)r * 512 + k0 + sko;
      *(us8*)&Bld[r][sko]     = *(const us8*)pb;
      *(us8*)&Bld[r][sko + 8] = *(const us8*)(pb + 8);
    }
    __syncthreads();
    mbf8 af[4][2], bf[4][2];
#pragma unroll
    for (int fi = 0; fi < 4; ++fi)
#pragma unroll
      for (int kh = 0; kh < 2; ++kh) {
        af[fi][kh] = *(const mbf8*)&Ald[wi * 64 + fi * 16 + (lane & 15)][kh * 32 + (lane >> 4) * 8];
        bf[fi][kh] = *(const mbf8*)&Bld[wj * 64 + fi * 16 + (lane & 15)][kh * 32 + (lane >> 4) * 8];
      }
#pragma unroll
    for (int fi = 0; fi < 4; ++fi)
#pragma unroll
      for (int fj = 0; fj < 4; ++fj)
#pragma unroll
        for (int kh = 0; kh < 2; ++kh)
          acc[fi][fj] = __builtin_amdgcn_mfma_f32_16x16x32_bf16(af[fi][kh], bf[fj][kh], acc[fi][fj], 0, 0, 0);
  }
#pragma unroll
  for (int fi = 0; fi < 4; ++fi)
#pragma unroll
    for (int fj = 0; fj < 4; ++fj) {
      int col = j0 + wj * 64 + fj * 16 + (lane & 15);
#pragma unroll
      for (int r = 0; r < 4; ++r) {
        int row = i0 + wi * 64 + fi * 16 + (lane >> 4) * 4 + r;
        float v = acc[fi][fj][r] + bias[BIASI ? row : col];
        if (RELU) v = fmaxf(v, 0.f);
        size_t off = (size_t)blockIdx.z * obatch + (size_t)row * orow + col;
        if (F32OUT) ((float*)outp)[off] = v;
        else        ((unsigned short*)outp)[off] = f2bf(v);
      }
    }
}

// ---- flash attention: Q,K (B,L,C) l-major bf16; V (B,C,L) d-major bf16 ----
// grid (L/64, NHEAD, B), 256 thr = 4 waves, wave w owns q rows w*16..w*16+15.
__global__ __launch_bounds__(256) void k_attn(const unsigned short* __restrict__ Q,
                                              const unsigned short* __restrict__ Kb,
                                              const unsigned short* __restrict__ Vb,
                                              const int* __restrict__ mask,
                                              unsigned short* __restrict__ out) {
  __shared__ __align__(16) unsigned short Qld[64][72];
  __shared__ __align__(16) unsigned short Kld[64][72];
  __shared__ __align__(16) unsigned short Vld[64][72];
  __shared__ __align__(16) unsigned short Pld[4][16][72];
  __shared__ int mld[LL];
  int t = threadIdx.x;
  int lane = t & 63, w = t >> 6;
  int q0 = blockIdx.x * 64;
  int h = blockIdx.y, b = blockIdx.z;
  for (int i = t; i < LL; i += 256) mld[i] = mask[(size_t)b * LL + i];
  {
    int r = t >> 2, ko = (t & 3) * 16;
    const unsigned short* src = Q + ((size_t)b * LL + q0 + r) * CC + h * DH + ko;
    *(us8*)&Qld[r][ko]     = *(const us8*)src;
    *(us8*)&Qld[r][ko + 8] = *(const us8*)(src + 8);
  }
  __syncthreads();
  mbf8 qf[2];
#pragma unroll
  for (int kh = 0; kh < 2; ++kh)
    qf[kh] = *(const mbf8*)&Qld[w * 16 + (lane & 15)][kh * 32 + (lane >> 4) * 8];
  f32x4 po[4];
  const f32x4 fz = {0.f, 0.f, 0.f, 0.f};
#pragma unroll
  for (int fd = 0; fd < 4; ++fd) po[fd] = fz;
  float rs[4] = {0.f, 0.f, 0.f, 0.f};
  int sr = t >> 2, sko = (t & 3) * 16;
  for (int kt = 0; kt < LL / 64; ++kt) {
    int k0 = kt * 64;
    __syncthreads();
    {
      const unsigned short* pk = Kb + ((size_t)b * LL + k0 + sr) * CC + h * DH + sko;
      *(us8*)&Kld[sr][sko]     = *(const us8*)pk;
      *(us8*)&Kld[sr][sko + 8] = *(const us8*)(pk + 8);
      const unsigned short* pv = Vb + ((size_t)b * CC + h * DH + sr) * LL + k0 + sko;
      *(us8*)&Vld[sr][sko]     = *(const us8*)pv;
      *(us8*)&Vld[sr][sko + 8] = *(const us8*)(pv + 8);
    }
    __syncthreads();
    f32x4 s[4];
#pragma unroll
    for (int fj = 0; fj < 4; ++fj) {
      s[fj] = fz;
#pragma unroll
      for (int kh = 0; kh < 2; ++kh) {
        mbf8 kf = *(const mbf8*)&Kld[fj * 16 + (lane & 15)][kh * 32 + (lane >> 4) * 8];
        s[fj] = __builtin_amdgcn_mfma_f32_16x16x32_bf16(qf[kh], kf, s[fj], 0, 0, 0);
      }
    }
    float trs[4] = {0.f, 0.f, 0.f, 0.f};
#pragma unroll
    for (int fj = 0; fj < 4; ++fj) {
      int mk = mld[k0 + fj * 16 + (lane & 15)];
#pragma unroll
      for (int r = 0; r < 4; ++r) {
        float e = mk ? __expf(s[fj][r] * 0.125f) : 0.f;
        unsigned short eb = f2bf(e);
        trs[r] += bf2f(eb);
        Pld[w][(lane >> 4) * 4 + r][fj * 16 + (lane & 15)] = eb;
      }
    }
#pragma unroll
    for (int r = 0; r < 4; ++r) {
#pragma unroll
      for (int m = 1; m < 16; m <<= 1) trs[r] += __shfl_xor(trs[r], m);
      rs[r] += trs[r];
    }
    mbf8 pf[2];
#pragma unroll
    for (int kh = 0; kh < 2; ++kh)
      pf[kh] = *(const mbf8*)&Pld[w][lane & 15][kh * 32 + (lane >> 4) * 8];
#pragma unroll
    for (int fd = 0; fd < 4; ++fd)
#pragma unroll
      for (int kh = 0; kh < 2; ++kh) {
        mbf8 vf = *(const mbf8*)&Vld[fd * 16 + (lane & 15)][kh * 32 + (lane >> 4) * 8];
        po[fd] = __builtin_amdgcn_mfma_f32_16x16x32_bf16(pf[kh], vf, po[fd], 0, 0, 0);
      }
  }
  float inv[4];
#pragma unroll
  for (int r = 0; r < 4; ++r) inv[r] = 1.0f / rs[r];
#pragma unroll
  for (int fd = 0; fd < 4; ++fd)
#pragma unroll
    for (int r = 0; r < 4; ++r) {
      int q = q0 + w * 16 + (lane >> 4) * 4 + r;
      int c = h * DH + fd * 16 + (lane & 15);
      out[((size_t)b * LL + q) * CC + c] = f2bf(po[fd][r] * inv[r]);
    }
}

extern "C" void kernel_launch(void* const* d_in, const int* in_sizes, int n_in,
                              void* d_out, int out_size, void* d_ws, size_t ws_size,
                              hipStream_t stream) {
  const float* x        = (const float*)d_in[0];
  const int*   mask     = (const int*)d_in[1];
  const float* dw_w     = (const float*)d_in[4];
  const float* pw_w     = (const float*)d_in[5];
  const float* pw_b     = (const float*)d_in[6];
  const float* cln_g    = (const float*)d_in[7];
  const float* cln_b    = (const float*)d_in[8];
  const float* w_kv     = (const float*)d_in[9];
  const float* b_kv     = (const float*)d_in[10];
  const float* w_q      = (const float*)d_in[11];
  const float* b_q      = (const float*)d_in[12];
  const float* ln_att_g = (const float*)d_in[13];
  const float* ln_att_b = (const float*)d_in[14];
  const float* w_ffd1   = (const float*)d_in[15];
  const float* b_ffd1   = (const float*)d_in[16];
  const float* w_ffd2   = (const float*)d_in[17];
  const float* b_ffd2   = (const float*)d_in[18];
  const float* ln_ffd_g = (const float*)d_in[19];
  const float* ln_ffd_b = (const float*)d_in[20];

  size_t actElems = (size_t)BB * LL * CC;
  unsigned short* A0 = (unsigned short*)d_ws;
  unsigned short* A1 = A0 + actElems;
  unsigned short* A2 = A1 + actElems;
  unsigned short* Vb = A2 + actElems;
  unsigned short* Wb = Vb + actElems;
  unsigned short* pw_bf = Wb;
  unsigned short* kv_bf = pw_bf + (size_t)4 * CC * CC;
  unsigned short* q_bf  = kv_bf + (size_t)2 * CC * CC;
  unsigned short* f1_bf = q_bf + (size_t)CC * CC;
  unsigned short* f2_bf = f1_bf + (size_t)CC * CC;

  long actB = (long)LL * CC;

  k_cvtW<<<2304, 256, 0, stream>>>(pw_w, w_kv, w_q, w_ffd1, w_ffd2, Wb);
  k_in_tr<<<dim3(8, 16, BB), 256, 0, stream>>>(x, A0);

  for (int i = 0; i < 4; ++i) {
    k_ln<<<4096, 256, 0, stream>>>(A0, cln_g + i * CC, cln_b + i * CC, A1);
    k_dwconv<<<4096, 256, 0, stream>>>(A1, dw_w + (size_t)i * CC * KW, A2);
    k_gemm<1, 0, 0><<<dim3(4, 8, BB), 256, 0, stream>>>(
        A2, actB, pw_bf + (size_t)i * CC * CC, 0, pw_b + i * CC, A0, 512, actB);
  }

  k_ln<<<4096, 256, 0, stream>>>(A0, ln_att_g, ln_att_b, A1);
  k_gemm<0, 0, 0><<<dim3(4, 8, BB), 256, 0, stream>>>(
      A1, actB, kv_bf, 0, b_kv, A2, 512, actB);                                  // K  (B,L,C)
  k_gemm<0, 0, 1><<<dim3(8, 4, BB), 256, 0, stream>>>(
      kv_bf + (size_t)CC * CC, 0, A1, actB, b_kv + CC, Vb, 1024, actB);          // V  (B,C,L)
  k_gemm<0, 0, 0><<<dim3(4, 8, BB), 256, 0, stream>>>(
      A1, actB, q_bf, 0, b_q, A0, 512, actB);                                    // Q  (B,L,C)
  k_attn<<<dim3(16, NHEAD, BB), 256, 0, stream>>>(A0, A2, Vb, mask, A1);

  k_ln<<<4096, 256, 0, stream>>>(A1, ln_ffd_g, ln_ffd_b, A2);
  k_gemm<1, 0, 0><<<dim3(4, 8, BB), 256, 0, stream>>>(
      A2, actB, f1_bf, 0, b_ffd1, A0, 512, actB);
  k_gemm<0, 1, 1><<<dim3(8, 4, BB), 256, 0, stream>>>(
      f2_bf, 0, A0, actB, b_ffd2, d_out, 1024, (long)CC * LL);
}

// Round 3
// 402.290 us; speedup vs baseline: 6.8382x; 1.3020x over previous
//
#include <hip/hip_runtime.h>
#include <math.h>

#define BB 16
#define CC 512
#define LL 1024
#define NHEAD 8
#define DH 64
#define KW 7

typedef unsigned short us;
typedef unsigned short us8 __attribute__((ext_vector_type(8)));
typedef unsigned short us4 __attribute__((ext_vector_type(4)));
typedef short mbf8 __attribute__((ext_vector_type(8)));
typedef float f32x4 __attribute__((ext_vector_type(4)));
typedef float f32x16 __attribute__((ext_vector_type(16)));

__device__ inline us f2bf(float f) {
  union { float f; unsigned int u; } v; v.f = f;
  unsigned int u = v.u;
  u += 0x7fffu + ((u >> 16) & 1u);
  return (us)(u >> 16);
}
__device__ inline float bf2f(us s) {
  union { unsigned int u; float f; } v; v.u = ((unsigned int)s) << 16;
  return v.f;
}

// global -> LDS direct 16B copy: lds dest = wave-uniform base + lane*16
__device__ __forceinline__ void gld16(const void* g, void* l) {
  __builtin_amdgcn_global_load_lds(
      (__attribute__((address_space(1))) unsigned int*)(uintptr_t)(g),
      (__attribute__((address_space(3))) unsigned int*)(unsigned int)(uintptr_t)(l),
      16, 0, 0);
}

// ---- weight fp32 -> bf16 pre-convert ----
__global__ __launch_bounds__(256) void k_cvtW(const float* __restrict__ p0,
                                              const float* __restrict__ p1,
                                              const float* __restrict__ p2,
                                              const float* __restrict__ p3,
                                              const float* __restrict__ p4,
                                              us* __restrict__ dst) {
  int idx = blockIdx.x * 256 + threadIdx.x;
  int e = idx * 4;
  const int n0 = 4 * CC * CC, n1 = 2 * CC * CC, n2 = CC * CC;
  const float* src; int off;
  if (e < n0)                { src = p0; off = e; }
  else if (e < n0 + n1)      { src = p1; off = e - n0; }
  else if (e < n0 + n1 + n2) { src = p2; off = e - n0 - n1; }
  else if (e < n0 + n1 + 2 * n2) { src = p3; off = e - n0 - n1 - n2; }
  else                       { src = p4; off = e - n0 - n1 - 2 * n2; }
  float4 v = *(const float4*)(src + off);
  us4 o; o[0] = f2bf(v.x); o[1] = f2bf(v.y); o[2] = f2bf(v.z); o[3] = f2bf(v.w);
  *(us4*)(dst + e) = o;
}

// ---- x (B,C,L) f32 -> Act (B,L,C) bf16 with timing signal ----
__global__ __launch_bounds__(256) void k_in_tr(const float* __restrict__ x,
                                               us* __restrict__ act) {
  __shared__ float xt[64][69];
  int t = threadIdx.x;
  int c0 = blockIdx.x * 64;
  int l0 = blockIdx.y * 64;
  int b  = blockIdx.z;
  {
    int r = t >> 2, lo2 = (t & 3) * 16;
    const float* src = x + ((size_t)b * CC + c0 + r) * LL + l0 + lo2;
#pragma unroll
    for (int q = 0; q < 4; ++q) {
      float4 v = *(const float4*)(src + q * 4);
      xt[r][lo2 + q * 4 + 0] = v.x; xt[r][lo2 + q * 4 + 1] = v.y;
      xt[r][lo2 + q * 4 + 2] = v.z; xt[r][lo2 + q * 4 + 3] = v.w;
    }
  }
  __syncthreads();
  const float log_inc = 9.210340371976184f / 255.0f;
  int lr = t >> 2, co = (t & 3) * 16;
  int l = l0 + lr;
  us obuf[16];
#pragma unroll
  for (int u = 0; u < 16; ++u) {
    int c = c0 + co + u;
    float inv = __expf(-(float)(c & 255) * log_inc);
    float st = (float)l * inv;
    float sg = (c < 256) ? sinf(st) : cosf(st);
    obuf[u] = f2bf(xt[co + u][lr] + sg);
  }
  us* dst = act + ((size_t)b * LL + l) * CC + c0 + co;
  *(us8*)dst = *(us8*)&obuf[0];
  *(us8*)(dst + 8) = *(us8*)&obuf[8];
}

// ---- row LayerNorm over C, (B,L,C) bf16 ----
__global__ __launch_bounds__(256) void k_ln(const us* __restrict__ in,
                                            const float* __restrict__ g,
                                            const float* __restrict__ bta,
                                            us* __restrict__ out) {
  int t = threadIdx.x;
  int lane = t & 63, w = t >> 6;
  size_t row = (size_t)blockIdx.x * 4 + w;
  const us* p = in + row * CC + lane * 8;
  us8 v = *(const us8*)p;
  float f[8]; float s = 0.f, ss = 0.f;
#pragma unroll
  for (int i = 0; i < 8; ++i) { f[i] = bf2f(v[i]); s += f[i]; ss += f[i] * f[i]; }
#pragma unroll
  for (int m = 1; m < 64; m <<= 1) { s += __shfl_xor(s, m); ss += __shfl_xor(ss, m); }
  float mean = s * (1.f / CC);
  float rstd = rsqrtf(ss * (1.f / CC) - mean * mean + 1e-5f);
  float4 g0 = *(const float4*)(g + lane * 8), g1 = *(const float4*)(g + lane * 8 + 4);
  float4 b0 = *(const float4*)(bta + lane * 8), b1 = *(const float4*)(bta + lane * 8 + 4);
  float gg[8] = {g0.x, g0.y, g0.z, g0.w, g1.x, g1.y, g1.z, g1.w};
  float bb2[8] = {b0.x, b0.y, b0.z, b0.w, b1.x, b1.y, b1.z, b1.w};
  us o[8];
#pragma unroll
  for (int i = 0; i < 8; ++i) o[i] = f2bf((f[i] - mean) * rstd * gg[i] + bb2[i]);
  *(us8*)(out + row * CC + lane * 8) = *(us8*)&o[0];
}

// ---- depthwise conv K=7 along L, (B,L,C) bf16 ----
__global__ __launch_bounds__(256) void k_dwconv(const us* __restrict__ in,
                                                const float* __restrict__ w,
                                                us* __restrict__ out) {
  __shared__ float wld[CC * KW];
  int t = threadIdx.x;
  for (int i = t; i < CC * KW; i += 256) wld[i] = w[i];
  __syncthreads();
  int c = (t & 63) * 8;
  int rowid = blockIdx.x * 4 + (t >> 6);
  int l = rowid & (LL - 1);
  int b = rowid >> 10;
  float acc[8] = {};
#pragma unroll
  for (int j = 0; j < KW; ++j) {
    int lj = l + j - 3;
    if (lj < 0 || lj >= LL) continue;
    us8 v = *(const us8*)(in + ((size_t)b * LL + lj) * CC + c);
#pragma unroll
    for (int u = 0; u < 8; ++u) acc[u] += bf2f(v[u]) * wld[(c + u) * KW + j];
  }
  us o[8];
#pragma unroll
  for (int u = 0; u < 8; ++u) o[u] = f2bf(acc[u]);
  *(us8*)(out + ((size_t)b * LL + l) * CC + c) = *(us8*)&o[0];
}

// ---- MFMA GEMM (m97-style): D[i][j] = oscale*(sum_k A[i][k]*B[j][k] + bias) ----
// A,B row-major bf16, row stride 512. 128x128 tile, BK=64, global_load_lds staging.
template <int RELU, int F32OUT, int BIASI>
__global__ __launch_bounds__(256) void k_gemm(const us* __restrict__ A, long Ab,
                                              const us* __restrict__ Bm, long Bb,
                                              const float* __restrict__ bias,
                                              void* __restrict__ outp,
                                              long orow, long obatch, float oscale) {
  __shared__ __align__(16) us Ald[128 * 64];
  __shared__ __align__(16) us Bld[128 * 64];
  int t = threadIdx.x;
  int lane = t & 63, w = t >> 6;
  int wi = w >> 1, wj = w & 1;
  int i0 = blockIdx.y * 128, j0 = blockIdx.x * 128;
  const us* Ag = A + (size_t)blockIdx.z * Ab + (size_t)i0 * 512;
  const us* Bg = Bm + (size_t)blockIdx.z * Bb + (size_t)j0 * 512;
  int rr = lane >> 3, cc8 = (lane & 7) * 8;
  f32x4 acc[4][4];
  const f32x4 fz = {0.f, 0.f, 0.f, 0.f};
#pragma unroll
  for (int a = 0; a < 4; ++a)
#pragma unroll
    for (int c = 0; c < 4; ++c) acc[a][c] = fz;
  for (int k0 = 0; k0 < 512; k0 += 64) {
    __syncthreads();
#pragma unroll
    for (int it = 0; it < 4; ++it) {
      int ch = w * 4 + it;  // wave-uniform chunk: 8 rows x 64 cols = 1KB
      gld16(Ag + (size_t)(ch * 8 + rr) * 512 + k0 + cc8, &Ald[ch * 512]);
      gld16(Bg + (size_t)(ch * 8 + rr) * 512 + k0 + cc8, &Bld[ch * 512]);
    }
    __syncthreads();  // drains vmcnt: gload data visible
    mbf8 af[4][2], bfr[4][2];
#pragma unroll
    for (int fi = 0; fi < 4; ++fi)
#pragma unroll
      for (int kh = 0; kh < 2; ++kh) {
        af[fi][kh]  = *(const mbf8*)&Ald[(wi * 64 + fi * 16 + (lane & 15)) * 64 + kh * 32 + (lane >> 4) * 8];
        bfr[fi][kh] = *(const mbf8*)&Bld[(wj * 64 + fi * 16 + (lane & 15)) * 64 + kh * 32 + (lane >> 4) * 8];
      }
#pragma unroll
    for (int fi = 0; fi < 4; ++fi)
#pragma unroll
      for (int fj = 0; fj < 4; ++fj)
#pragma unroll
        for (int kh = 0; kh < 2; ++kh)
          acc[fi][fj] = __builtin_amdgcn_mfma_f32_16x16x32_bf16(af[fi][kh], bfr[fj][kh], acc[fi][fj], 0, 0, 0);
  }
#pragma unroll
  for (int fi = 0; fi < 4; ++fi)
#pragma unroll
    for (int fj = 0; fj < 4; ++fj) {
      int col = j0 + wj * 64 + fj * 16 + (lane & 15);
#pragma unroll
      for (int r = 0; r < 4; ++r) {
        int row = i0 + wi * 64 + fi * 16 + (lane >> 4) * 4 + r;
        float v = (acc[fi][fj][r] + bias[BIASI ? row : col]) * oscale;
        if (RELU) v = fmaxf(v, 0.f);
        size_t off = (size_t)blockIdx.z * obatch + (size_t)row * orow + col;
        if (F32OUT) ((float*)outp)[off] = v;
        else        ((us*)outp)[off] = f2bf(v);
      }
    }
}

// ---- flash attention, swapped-QK 32x32 structure ----
// Q,K (B,L,C) bf16 (Q pre-scaled by 0.125); V (B,C,L) bf16.
// grid (L/128, NHEAD, B), 256 thr = 4 waves; wave owns 32 q rows.
__global__ __launch_bounds__(256) void k_attn(const us* __restrict__ Q,
                                              const us* __restrict__ Kb,
                                              const us* __restrict__ Vb,
                                              const int* __restrict__ mask,
                                              us* __restrict__ out) {
  __shared__ __align__(16) us Kld[64][72];  // [k][d]
  __shared__ __align__(16) us Vld[64][72];  // [d][k]
  __shared__ unsigned int mbits[32];
  __shared__ float rsld[128];
  int t = threadIdx.x;
  int lane = t & 63, w = t >> 6;
  int lo = lane & 31, hi = lane >> 5;
  int q0 = blockIdx.x * 128;
  int h = blockIdx.y, b = blockIdx.z;

  // mask -> bit array (1024 bits)
#pragma unroll
  for (int j = 0; j < 4; ++j) {
    int k = w * 256 + j * 64 + lane;
    unsigned long long bl = __ballot(mask[(size_t)b * LL + k] != 0);
    if (lane == 0) {
      mbits[w * 8 + j * 2]     = (unsigned int)bl;
      mbits[w * 8 + j * 2 + 1] = (unsigned int)(bl >> 32);
    }
  }

  // Q fragments direct from global: B[j=lo->q][d = ds*16 + hi*8 + e]
  mbf8 qf[4];
  {
    const us* qp = Q + ((size_t)b * LL + q0 + w * 32 + lo) * CC + h * DH + hi * 8;
#pragma unroll
    for (int ds = 0; ds < 4; ++ds) qf[ds] = *(const mbf8*)(qp + ds * 16);
  }

  // prefetch tile 0 into regs
  int sr = t >> 2, sko = (t & 3) * 16;
  const us* pkbase = Kb + ((size_t)b * LL + sr) * CC + h * DH + sko;
  const us* pvbase = Vb + ((size_t)b * CC + h * DH + sr) * LL + sko;
  us8 kr0 = *(const us8*)pkbase, kr1 = *(const us8*)(pkbase + 8);
  us8 vr0 = *(const us8*)pvbase, vr1 = *(const us8*)(pvbase + 8);

  const f32x16 Z16 = {0,0,0,0,0,0,0,0,0,0,0,0,0,0,0,0};
  f32x16 po0 = Z16, po1 = Z16;
  float rs = 0.f;

  for (int kt = 0; kt < 16; ++kt) {
    // barrier1: all readers of Kld/Vld done (lgkm-only, vmcnt stays in flight)
    asm volatile("s_waitcnt lgkmcnt(0)" ::: "memory");
    __builtin_amdgcn_s_barrier();
    asm volatile("" ::: "memory");
    *(us8*)&Kld[sr][sko]     = kr0;  *(us8*)&Kld[sr][sko + 8] = kr1;
    *(us8*)&Vld[sr][sko]     = vr0;  *(us8*)&Vld[sr][sko + 8] = vr1;
    if (kt < 15) {  // issue next-tile loads; latency hides under compute below
      const us* pk = pkbase + (size_t)(kt + 1) * 64 * CC;
      const us* pv = pvbase + (kt + 1) * 64;
      kr0 = *(const us8*)pk; kr1 = *(const us8*)(pk + 8);
      vr0 = *(const us8*)pv; vr1 = *(const us8*)(pv + 8);
    }
    // barrier2: staging visible (lgkm-only)
    asm volatile("s_waitcnt lgkmcnt(0)" ::: "memory");
    __builtin_amdgcn_s_barrier();
    asm volatile("" ::: "memory");

    // QK^T swapped: S^T[k][q], k-tiles 0/1
    f32x16 s0 = Z16, s1 = Z16;
#pragma unroll
    for (int ds = 0; ds < 4; ++ds) {
      mbf8 kf0 = *(const mbf8*)&Kld[lo][ds * 16 + hi * 8];
      mbf8 kf1 = *(const mbf8*)&Kld[32 + lo][ds * 16 + hi * 8];
      s0 = __builtin_amdgcn_mfma_f32_32x32x16_bf16(kf0, qf[ds], s0, 0, 0, 0);
      s1 = __builtin_amdgcn_mfma_f32_32x32x16_bf16(kf1, qf[ds], s1, 0, 0, 0);
    }
    // mask + exp (k row of reg r = (r&3)+8*(r>>2)+4*hi)
    uint2 mbp = *(const uint2*)&mbits[kt * 2];
    float p0[16], p1[16];
#pragma unroll
    for (int r = 0; r < 16; ++r) {
      int kl = (r & 3) + 8 * (r >> 2) + hi * 4;
      float e0v = ((mbp.x >> kl) & 1u) ? __expf(s0[r]) : 0.f;
      float e1v = ((mbp.y >> kl) & 1u) ? __expf(s1[r]) : 0.f;
      p0[r] = e0v; p1[r] = e1v;
      rs += e0v + e1v;
    }
    // pack P -> bf16 A-frags via cvt_pk + permlane32_swap, then PV
#define PVSTEP(P, KOFF, KS)                                                          \
    {                                                                                \
      int x0, x1, y0, y1;                                                            \
      asm("v_cvt_pk_bf16_f32 %0, %1, %2" : "=v"(x0) : "v"(P[8*KS+0]), "v"(P[8*KS+1])); \
      asm("v_cvt_pk_bf16_f32 %0, %1, %2" : "=v"(x1) : "v"(P[8*KS+2]), "v"(P[8*KS+3])); \
      asm("v_cvt_pk_bf16_f32 %0, %1, %2" : "=v"(y0) : "v"(P[8*KS+4]), "v"(P[8*KS+5])); \
      asm("v_cvt_pk_bf16_f32 %0, %1, %2" : "=v"(y1) : "v"(P[8*KS+6]), "v"(P[8*KS+7])); \
      asm("v_permlane32_swap_b32 %0, %1" : "+v"(x0), "+v"(y0));                      \
      asm("v_permlane32_swap_b32 %0, %1" : "+v"(x1), "+v"(y1));                      \
      union { int i[4]; mbf8 v; } fr;                                                \
      fr.i[0] = x0; fr.i[1] = x1; fr.i[2] = y0; fr.i[3] = y1;                        \
      mbf8 vf0 = *(const mbf8*)&Vld[lo][(KOFF) + (KS) * 16 + hi * 8];                \
      mbf8 vf1 = *(const mbf8*)&Vld[32 + lo][(KOFF) + (KS) * 16 + hi * 8];           \
      po0 = __builtin_amdgcn_mfma_f32_32x32x16_bf16(fr.v, vf0, po0, 0, 0, 0);        \
      po1 = __builtin_amdgcn_mfma_f32_32x32x16_bf16(fr.v, vf1, po1, 0, 0, 0);        \
    }
    PVSTEP(p0, 0, 0)
    PVSTEP(p0, 0, 1)
    PVSTEP(p1, 32, 0)
    PVSTEP(p1, 32, 1)
#undef PVSTEP
  }

  // rowsum across halves -> inverse, via wave-private LDS slice
  rs += __shfl_xor(rs, 32);
  if (hi == 0) rsld[w * 32 + lo] = 1.0f / rs;
  // same-wave LDS dep: compiler inserts lgkm wait
#define WRITEO(PO, DT)                                                               \
  {                                                                                  \
    _Pragma("unroll")                                                                \
    for (int r = 0; r < 16; ++r) {                                                   \
      int qrow = (r & 3) + 8 * (r >> 2) + 4 * hi;                                    \
      float iv = rsld[w * 32 + qrow];                                                \
      out[((size_t)b * LL + q0 + w * 32 + qrow) * CC + h * DH + (DT) * 32 + lo]      \
          = f2bf(PO[r] * iv);                                                        \
    }                                                                                \
  }
  WRITEO(po0, 0)
  WRITEO(po1, 1)
#undef WRITEO
}

extern "C" void kernel_launch(void* const* d_in, const int* in_sizes, int n_in,
                              void* d_out, int out_size, void* d_ws, size_t ws_size,
                              hipStream_t stream) {
  const float* x        = (const float*)d_in[0];
  const int*   mask     = (const int*)d_in[1];
  const float* dw_w     = (const float*)d_in[4];
  const float* pw_w     = (const float*)d_in[5];
  const float* pw_b     = (const float*)d_in[6];
  const float* cln_g    = (const float*)d_in[7];
  const float* cln_b    = (const float*)d_in[8];
  const float* w_kv     = (const float*)d_in[9];
  const float* b_kv     = (const float*)d_in[10];
  const float* w_q      = (const float*)d_in[11];
  const float* b_q      = (const float*)d_in[12];
  const float* ln_att_g = (const float*)d_in[13];
  const float* ln_att_b = (const float*)d_in[14];
  const float* w_ffd1   = (const float*)d_in[15];
  const float* b_ffd1   = (const float*)d_in[16];
  const float* w_ffd2   = (const float*)d_in[17];
  const float* b_ffd2   = (const float*)d_in[18];
  const float* ln_ffd_g = (const float*)d_in[19];
  const float* ln_ffd_b = (const float*)d_in[20];

  size_t actElems = (size_t)BB * LL * CC;
  us* A0 = (us*)d_ws;
  us* A1 = A0 + actElems;
  us* A2 = A1 + actElems;
  us* Vb = A2 + actElems;
  us* Wb = Vb + actElems;
  us* pw_bf = Wb;
  us* kv_bf = pw_bf + (size_t)4 * CC * CC;
  us* q_bf  = kv_bf + (size_t)2 * CC * CC;
  us* f1_bf = q_bf + (size_t)CC * CC;
  us* f2_bf = f1_bf + (size_t)CC * CC;

  long actB = (long)LL * CC;

  k_cvtW<<<2304, 256, 0, stream>>>(pw_w, w_kv, w_q, w_ffd1, w_ffd2, Wb);
  k_in_tr<<<dim3(8, 16, BB), 256, 0, stream>>>(x, A0);

  for (int i = 0; i < 4; ++i) {
    k_ln<<<4096, 256, 0, stream>>>(A0, cln_g + i * CC, cln_b + i * CC, A1);
    k_dwconv<<<4096, 256, 0, stream>>>(A1, dw_w + (size_t)i * CC * KW, A2);
    k_gemm<1, 0, 0><<<dim3(4, 8, BB), 256, 0, stream>>>(
        A2, actB, pw_bf + (size_t)i * CC * CC, 0, pw_b + i * CC, A0, 512, actB, 1.0f);
  }

  k_ln<<<4096, 256, 0, stream>>>(A0, ln_att_g, ln_att_b, A1);
  k_gemm<0, 0, 0><<<dim3(4, 8, BB), 256, 0, stream>>>(
      A1, actB, kv_bf, 0, b_kv, A2, 512, actB, 1.0f);                              // K (B,L,C)
  k_gemm<0, 0, 1><<<dim3(8, 4, BB), 256, 0, stream>>>(
      kv_bf + (size_t)CC * CC, 0, A1, actB, b_kv + CC, Vb, 1024, actB, 1.0f);      // V (B,C,L)
  k_gemm<0, 0, 0><<<dim3(4, 8, BB), 256, 0, stream>>>(
      A1, actB, q_bf, 0, b_q, A0, 512, actB, 0.125f);                              // Q scaled
  k_attn<<<dim3(8, NHEAD, BB), 256, 0, stream>>>(A0, A2, Vb, mask, A1);

  k_ln<<<4096, 256, 0, stream>>>(A1, ln_ffd_g, ln_ffd_b, A2);
  k_gemm<1, 0, 0><<<dim3(4, 8, BB), 256, 0, stream>>>(
      A2, actB, f1_bf, 0, b_ffd1, A0, 512, actB, 1.0f);
  k_gemm<0, 1, 1><<<dim3(8, 4, BB), 256, 0, stream>>>(
      f2_bf, 0, A0, actB, b_ffd2, d_out, 1024, (long)CC * LL, 1.0f);
}